// Round 13
// baseline (170.537 us; speedup 1.0000x reference)
//
#include <hip/hip_runtime.h>
#include <hip/hip_bf16.h>
#include <math.h>

// B=2, T=2048, C=1024, H=16, D=64.  Inputs f32 (runtime-detected), compute bf16 MFMA.
// 4 launches: prep -> gemm_qkv (planar q/k + transposed V epilogue) -> attn -> gemm_nt.

typedef __attribute__((ext_vector_type(8))) short bf16x8;
typedef __attribute__((ext_vector_type(4))) float f32x4;

__device__ __forceinline__ float b2f(unsigned short u) {
    union { unsigned int i; float f; } x; x.i = ((unsigned int)u) << 16; return x.f;
}
__device__ __forceinline__ unsigned short f2b(float f) {
    __hip_bfloat16 h = __float2bfloat16(f);
    return *reinterpret_cast<unsigned short*>(&h);
}
__device__ __forceinline__ unsigned short f2b_rz(float f) {   // truncate (P only)
    union { float f; unsigned int i; } u; u.f = f; return (unsigned short)(u.i >> 16);
}
__device__ __forceinline__ float fexp2(float x) {
#if __has_builtin(__builtin_amdgcn_exp2f)
    return __builtin_amdgcn_exp2f(x);
#else
    return exp2f(x);
#endif
}
__device__ __forceinline__ void gload_lds16(const void* g, void* l) {
    __builtin_amdgcn_global_load_lds(
        (__attribute__((address_space(1))) void*)g,
        (__attribute__((address_space(3))) void*)l, 16, 0, 0);
}

// ---------------------------------------------------------------------------
// Fused prep: per-block dtype self-detect, then
//   blocks [0,1024): x -> xb (4096 elems each)
//   [1024,1792): Wqkv^T 64x64 tiles (Q cols scaled)   [1792,2048): Wo^T
//   2048: bias + publish flag
// Transpose is fully vectorized this round: float4/ushort4 loads (16 B/lane),
// ushort4 transposed stores (8 B/lane -> 4x fewer store insts, 4x coalescing).
// ---------------------------------------------------------------------------
__device__ __forceinline__ void transpose_job64(
        const void* __restrict__ in, unsigned short* __restrict__ out,
        int Cc, int use_bf, int nscale, float scale,
        int c0, int r0, int tid, unsigned short (*t)[65]) {
    const unsigned short* inb = (const unsigned short*)in;
    const float* inf = (const float*)in;
    const int xl = (tid & 15) * 4;           // 4-col group within tile
    const int y  = tid >> 4;                 // 16 rows per pass
    const float sc = (c0 < nscale) ? scale : 1.0f;   // tile-uniform (c0 64-aligned)
    #pragma unroll
    for (int p = 0; p < 4; p++) {
        int row = y + 16 * p;
        float v0, v1, v2, v3;
        if (use_bf) {
            ushort4 u = *(const ushort4*)(inb + (size_t)(r0 + row) * Cc + c0 + xl);
            v0 = b2f(u.x); v1 = b2f(u.y); v2 = b2f(u.z); v3 = b2f(u.w);
        } else {
            float4 f = *(const float4*)(inf + (size_t)(r0 + row) * Cc + c0 + xl);
            v0 = f.x; v1 = f.y; v2 = f.z; v3 = f.w;
        }
        t[row][xl + 0] = f2b(v0 * sc);
        t[row][xl + 1] = f2b(v1 * sc);
        t[row][xl + 2] = f2b(v2 * sc);
        t[row][xl + 3] = f2b(v3 * sc);
    }
    __syncthreads();
    const int rr = (tid & 15) * 4;           // 4-row group of output
    const int cc = tid >> 4;
    #pragma unroll
    for (int p = 0; p < 4; p++) {
        int ccp = cc + 16 * p;
        ushort4 o4;
        o4.x = t[rr + 0][ccp];
        o4.y = t[rr + 1][ccp];
        o4.z = t[rr + 2][ccp];
        o4.w = t[rr + 3][ccp];
        *(ushort4*)(out + (size_t)(c0 + ccp) * 1024 + r0 + rr) = o4;
    }
}

__global__ __launch_bounds__(256) void prep_kernel(
        const void* __restrict__ xin, const void* __restrict__ Wqkv,
        const void* __restrict__ Wo, const void* __restrict__ bias,
        unsigned short* __restrict__ xb, unsigned short* __restrict__ WqkvT,
        unsigned short* __restrict__ WoT, unsigned short* __restrict__ bob,
        int* __restrict__ flag, float qscale) {
    __shared__ __align__(16) unsigned short t[64][65];
    __shared__ int det;
    const int tid = threadIdx.x, blk = blockIdx.x;

    if (tid < 64) {
        const unsigned short* xu = (const unsigned short*)xin;
        int cnt = 0;
        for (int i = tid; i < 1024; i += 64) {
            unsigned short u = xu[2 * i];
            int e = (u >> 7) & 0xFF;
            if (!((e == 0) || (e >= 96 && e <= 159))) cnt++;
        }
        #pragma unroll
        for (int m = 1; m < 64; m <<= 1) cnt += __shfl_xor(cnt, m);
        if (tid == 0) det = (cnt > 200) ? 0 : 1;
    }
    __syncthreads();
    const int use_bf = det;

    if (blk < 1024) {                       // x convert: 4096 elems/block
        int base = blk * 4096;
        #pragma unroll
        for (int i = 0; i < 4; i++) {
            int i4 = base + (tid + 256 * i) * 4;
            if (use_bf) {
                *(ushort4*)(xb + i4) = *(const ushort4*)((const unsigned short*)xin + i4);
            } else {
                float4 f = *(const float4*)((const float*)xin + i4);
                ushort4 o;
                o.x = f2b(f.x); o.y = f2b(f.y); o.z = f2b(f.z); o.w = f2b(f.w);
                *(ushort4*)(xb + i4) = o;
            }
        }
    } else if (blk < 1792) {                // Wqkv^T: 48 x 16 tiles of 64x64
        int tt = blk - 1024;
        int c0 = (tt % 48) * 64, r0 = (tt / 48) * 64;
        transpose_job64(Wqkv, WqkvT, 3072, use_bf, 1024, qscale, c0, r0, tid, t);
    } else if (blk < 2048) {                // Wo^T: 16 x 16 tiles
        int tt = blk - 1792;
        int c0 = (tt & 15) * 64, r0 = (tt >> 4) * 64;
        transpose_job64(Wo, WoT, 1024, use_bf, 0, 1.0f, c0, r0, tid, t);
    } else {
        int i4 = tid * 4;
        if (use_bf) {
            *(ushort4*)(bob + i4) = *(const ushort4*)((const unsigned short*)bias + i4);
        } else {
            float4 f = *(const float4*)((const float*)bias + i4);
            ushort4 o;
            o.x = f2b(f.x); o.y = f2b(f.y); o.z = f2b(f.z); o.w = f2b(f.w);
            *(ushort4*)(bob + i4) = o;
        }
        if (tid == 0) *flag = use_bf;
    }
}

// ---------------------------------------------------------------------------
// GEMM1: qkv = xb @ WqkvT^T.  128x192 (MxN) tiles -> grid (16,32) = 512 blocks
// = exactly 2 blocks/CU.  256 threads = 4 waves in 2x2; each wave owns 64x96
// (acc[4][6]).  LDS 40 KB.  (r6 measured winner)
// Swizzled LDS: elem (row,k) at row*64 + ((k>>3 ^ (row&7))<<3) + (k&7).
// ---------------------------------------------------------------------------
__global__ __launch_bounds__(256, 2) void gemm_qkv(
        const unsigned short* __restrict__ A, const unsigned short* __restrict__ Bt,
        unsigned short* __restrict__ qb, unsigned short* __restrict__ kb,
        unsigned short* __restrict__ vt) {
    __shared__ __align__(16) unsigned short lA[128 * 64];
    __shared__ __align__(16) unsigned short lB[192 * 64];
    const int tid  = threadIdx.x;
    const int wave = tid >> 6, lane = tid & 63;
    const int g = lane >> 4, c = lane & 15;
    const int m0 = blockIdx.y * 128, n0 = blockIdx.x * 192;
    const int wr = (wave >> 1) * 64;          // wave's M half (0 or 64)
    const int wc = (wave & 1) * 96;           // wave's N half (0 or 96)
    const int srow = lane >> 3;
    const int sc8  = ((lane & 7) ^ ((lane >> 3) & 7)) * 8;

    f32x4 acc[4][6] = {};

    for (int k0 = 0; k0 < 1024; k0 += 64) {
        #pragma unroll
        for (int i = 0; i < 4; i++) {         // A: 128 rows -> 16 segs (4/wave)
            int seg = wave * 4 + i;
            int row = seg * 8 + srow;
            gload_lds16(A  + (size_t)(m0 + row) * 1024 + k0 + sc8, lA + seg * 512);
        }
        #pragma unroll
        for (int i = 0; i < 6; i++) {         // B: 192 rows -> 24 segs (6/wave)
            int seg = wave * 6 + i;
            int row = seg * 8 + srow;
            gload_lds16(Bt + (size_t)(n0 + row) * 1024 + k0 + sc8, lB + seg * 512);
        }
        __syncthreads();

        #pragma unroll
        for (int dk = 0; dk < 2; dk++) {
            const int off = ((4 * dk + g) ^ (c & 7)) << 3;
            bf16x8 af[4], bfv[6];
            #pragma unroll
            for (int i = 0; i < 4; i++)
                af[i]  = *(const bf16x8*)(lA + (wr + 16 * i + c) * 64 + off);
            #pragma unroll
            for (int i = 0; i < 6; i++)
                bfv[i] = *(const bf16x8*)(lB + (wc + 16 * i + c) * 64 + off);
            #pragma unroll
            for (int mi = 0; mi < 4; mi++)
                #pragma unroll
                for (int ni = 0; ni < 6; ni++)
                    acc[mi][ni] = __builtin_amdgcn_mfma_f32_16x16x32_bf16(
                        af[mi], bfv[ni], acc[mi][ni], 0, 0, 0);
        }
        __syncthreads();
    }

    // Epilogue: per-fragment plane routing.  colbase is 16-aligned, so a
    // fragment (16 cols) never crosses a 64-aligned head or 1024-aligned
    // plane boundary.
    const int bb  = m0 >> 11;                 // batch (tile never crosses)
    const int kvb = (m0 & 2047) + wr;
    #pragma unroll
    for (int ni = 0; ni < 6; ni++) {
        const int colbase = n0 + wc + 16 * ni;
        if (colbase < 2048) {                 // q or k plane
            unsigned short* dst = (colbase < 1024) ? qb : kb;
            const int cb = (colbase & 1023) + c;
            #pragma unroll
            for (int mi = 0; mi < 4; mi++)
                #pragma unroll
                for (int r = 0; r < 4; r++) {
                    int row = m0 + wr + 16 * mi + 4 * g + r;
                    dst[(size_t)row * 1024 + cb] = f2b(acc[mi][ni][r]);
                }
        } else {                              // v -> vt[bh][d][kv]
            const int cc2 = colbase - 2048;
            const int hb  = cc2 >> 6;
            const int d   = (cc2 & 63) + c;
            const int bh  = bb * 16 + hb;
            #pragma unroll
            for (int mi = 0; mi < 4; mi++) {
                int kv = kvb + 16 * mi + 4 * g;   // rows r=0..3 consecutive
                ushort4 pk;
                pk.x = f2b(acc[mi][ni][0]); pk.y = f2b(acc[mi][ni][1]);
                pk.z = f2b(acc[mi][ni][2]); pk.w = f2b(acc[mi][ni][3]);
                *(ushort4*)(vt + ((size_t)bh * 64 + d) * 2048 + kv) = pk;
            }
        }
    }
}

// ---------------------------------------------------------------------------
// GEMM2: C = A @ Bt^T + bias.  128x64 tiles -> grid 512 (2 blocks/CU).
// ---------------------------------------------------------------------------
__global__ __launch_bounds__(256) void gemm_nt(
        const unsigned short* __restrict__ A, const unsigned short* __restrict__ Bt,
        void* __restrict__ C, const unsigned short* __restrict__ bias,
        const int* __restrict__ out_f32_flag, int M, int N, int K) {
    __shared__ __align__(16) unsigned short lA[128 * 64];
    __shared__ __align__(16) unsigned short lB[64 * 64];
    const int tid  = threadIdx.x;
    const int wave = tid >> 6, lane = tid & 63;
    const int g = lane >> 4, c = lane & 15;
    const int m0 = blockIdx.y * 128, n0 = blockIdx.x * 64;
    const int wm = wave * 32;
    const int srow = lane >> 3;
    const int sc8  = ((lane & 7) ^ ((lane >> 3) & 7)) * 8;

    f32x4 acc[2][4] = {};

    for (int k0 = 0; k0 < K; k0 += 64) {
        #pragma unroll
        for (int i = 0; i < 4; i++) {
            int seg = wave * 4 + i;
            int row = seg * 8 + srow;
            gload_lds16(A + (size_t)(m0 + row) * K + k0 + sc8, lA + seg * 512);
        }
        #pragma unroll
        for (int i = 0; i < 2; i++) {
            int seg = wave * 2 + i;
            int row = seg * 8 + srow;
            gload_lds16(Bt + (size_t)(n0 + row) * K + k0 + sc8, lB + seg * 512);
        }
        __syncthreads();

        #pragma unroll
        for (int dk = 0; dk < 2; dk++) {
            const int off = ((4 * dk + g) ^ (c & 7)) << 3;
            bf16x8 af[2], bfv[4];
            #pragma unroll
            for (int i = 0; i < 2; i++)
                af[i]  = *(const bf16x8*)(lA + (wm + 16 * i + c) * 64 + off);
            #pragma unroll
            for (int i = 0; i < 4; i++)
                bfv[i] = *(const bf16x8*)(lB + (16 * i + c) * 64 + off);
            #pragma unroll
            for (int mi = 0; mi < 2; mi++)
                #pragma unroll
                for (int ni = 0; ni < 4; ni++)
                    acc[mi][ni] = __builtin_amdgcn_mfma_f32_16x16x32_bf16(
                        af[mi], bfv[ni], acc[mi][ni], 0, 0, 0);
        }
        __syncthreads();
    }

    const bool f32out = out_f32_flag && (*out_f32_flag == 0);
    #pragma unroll
    for (int mi = 0; mi < 2; mi++)
        #pragma unroll
        for (int ni = 0; ni < 4; ni++)
            #pragma unroll
            for (int r = 0; r < 4; r++) {
                int row = m0 + wm + 16 * mi + 4 * g + r;
                int col = n0 + 16 * ni + c;
                float v = acc[mi][ni][r];
                if (bias) v += b2f(bias[col]);
                if (f32out) ((float*)C)[(size_t)row * N + col] = v;
                else ((unsigned short*)C)[(size_t)row * N + col] = f2b(v);
            }
}

// ---------------------------------------------------------------------------
// Flash attention, causal, fixed-offset softmax p = exp2(s - 12).
// S^T formulation, swizzled LDS, 64-row Q tiles, uniform work pairing.
// (r12 winner: no hardware lgkmcnt between P writes and pf reads -- per-wave
// LDS ops complete in order; V-fragment reads hoisted above the softmax.)
// ---------------------------------------------------------------------------
template<bool MASKED>
__device__ __forceinline__ void tile_compute(
        const unsigned short* __restrict__ lKs, const unsigned short* __restrict__ lVts,
        unsigned short* __restrict__ P, const bf16x8* qB, f32x4* o,
        float& l_run, int wave, int lane, int g, int c) {
    const f32x4 sinit = {-12.f, -12.f, -12.f, -12.f};   // offset folded into acc init
    f32x4 s[4] = {sinit, sinit, sinit, sinit};
    #pragma unroll
    for (int nt = 0; nt < 4; nt++)
        #pragma unroll
        for (int dk = 0; dk < 2; dk++) {
            bf16x8 kA = *(const bf16x8*)(lKs + (16 * nt + c) * 64 + (((4 * dk + g) ^ (c & 7)) << 3));
            s[nt] = __builtin_amdgcn_mfma_f32_16x16x32_bf16(kA, qB[dk], s[nt], 0, 0, 0);
        }

    // V fragments: issue now -- LDS latency hides under the softmax VALU.
    bf16x8 vf[4][2];
    #pragma unroll
    for (int ni = 0; ni < 4; ni++)
        #pragma unroll
        for (int kk = 0; kk < 2; kk++)
            vf[ni][kk] = *(const bf16x8*)(lVts + (16 * ni + c) * 64 + (((4 * kk + g) ^ (c & 7)) << 3));

    float rsum = 0.f;
    #pragma unroll
    for (int nt = 0; nt < 4; nt++) {
        unsigned long long pk = 0;
        #pragma unroll
        for (int r = 0; r < 4; r++) {
            float v = s[nt][r];
            if (MASKED) v = (16 * nt + 4 * g + r <= 16 * wave + c) ? v : -1e30f;
            float p = fexp2(v);
            rsum += p;
            pk |= ((unsigned long long)f2b_rz(p)) << (16 * r);
        }
        int kvl = 16 * nt + 4 * g;    // 4-aligned; r=0..3 stay in the same 8-slot
        *(unsigned long long*)(P + c * 64 + (((kvl >> 3) ^ (c & 7)) << 3) + (kvl & 7)) = pk;
    }
    rsum += __shfl_xor(rsum, 16);
    rsum += __shfl_xor(rsum, 32);
    l_run += rsum;

    // Compiler-order fence only: per-wave LDS ops complete in order (HW), so
    // the pf reads (issued after the writes) see the new P without a waitcnt.
    __asm__ volatile("" ::: "memory");

    bf16x8 pf[2];
    #pragma unroll
    for (int kk = 0; kk < 2; kk++)
        pf[kk] = *(const bf16x8*)(P + c * 64 + (((4 * kk + g) ^ (c & 7)) << 3));
    #pragma unroll
    for (int ni = 0; ni < 4; ni++)
        #pragma unroll
        for (int kk = 0; kk < 2; kk++)
            o[ni] = __builtin_amdgcn_mfma_f32_16x16x32_bf16(pf[kk], vf[ni][kk], o[ni], 0, 0, 0);
    __asm__ volatile("" ::: "memory");   // pin pf reads before next tile's P writes
}

__global__ __launch_bounds__(256, 2) void attn_kernel(
        const unsigned short* __restrict__ qb, const unsigned short* __restrict__ kb,
        const unsigned short* __restrict__ vt, unsigned short* __restrict__ Y) {
    __shared__ __align__(16) unsigned short lK[2][4096];
    __shared__ __align__(16) unsigned short lVt[2][4096];
    __shared__ __align__(16) unsigned short Pbuf[4][1024];

    const int tid = threadIdx.x, wave = tid >> 6, lane = tid & 63;
    const int g = lane >> 4, c = lane & 15;
    unsigned short* P = Pbuf[wave];
    const int srow = lane >> 3;
    const int sc8  = ((lane & 7) ^ ((lane >> 3) & 7)) * 8;

    // 512 uniform blocks: bh = blk & 31, jp = blk >> 5 (0..15).
    // Item 0: q-tile j = jp; item 1: q-tile j = 31 - jp (same bh -> K/V
    // pointers identical, L2-warm).  Total per block = (jp+1)+(32-jp) = 33.
    const int bh = blockIdx.x & 31;
    const int jp = blockIdx.x >> 5;
    const int b = bh >> 4, h = bh & 15;

    const unsigned short* Qb  = qb + (size_t)b * 2048 * 1024 + h * 64;
    const unsigned short* Kb  = kb + (size_t)b * 2048 * 1024 + h * 64;
    const unsigned short* Vtb = vt + (size_t)bh * 64 * 2048;

    #pragma unroll 1
    for (int item = 0; item < 2; item++) {
        const int j  = item ? (31 - jp) : jp;
        const int q0 = j * 64;
        const int rbase = q0 + 16 * wave;

        bf16x8 qB[2];
        #pragma unroll
        for (int dk = 0; dk < 2; dk++)
            qB[dk] = *(const bf16x8*)(Qb + (size_t)(rbase + c) * 1024 + 32 * dk + 8 * g);

        f32x4 o[4] = {};
        float l_run = 0.f;

        #pragma unroll 1
        for (int kv0 = 0; kv0 <= q0; kv0 += 128) {
            const bool do1 = (kv0 + 64 <= q0);
            #pragma unroll
            for (int i = 0; i < 2; i++) {
                int seg = wave * 2 + i;
                int row = seg * 8 + srow;
                gload_lds16(Kb  + (size_t)(kv0 + row) * 1024 + sc8, lK[0] + seg * 512);
                gload_lds16(Vtb + (size_t)row * 2048 + kv0 + sc8,   lVt[0] + seg * 512);
                if (do1) {
                    gload_lds16(Kb  + (size_t)(kv0 + 64 + row) * 1024 + sc8, lK[1] + seg * 512);
                    gload_lds16(Vtb + (size_t)row * 2048 + kv0 + 64 + sc8,   lVt[1] + seg * 512);
                }
            }
            __syncthreads();

            if (kv0 == q0)
                tile_compute<true >(lK[0], lVt[0], P, qB, o, l_run, wave, lane, g, c);
            else
                tile_compute<false>(lK[0], lVt[0], P, qB, o, l_run, wave, lane, g, c);
            if (do1) {
                if (kv0 + 64 == q0)
                    tile_compute<true >(lK[1], lVt[1], P, qB, o, l_run, wave, lane, g, c);
                else
                    tile_compute<false>(lK[1], lVt[1], P, qB, o, l_run, wave, lane, g, c);
            }
            __syncthreads();
        }

        float inv = 1.f / l_run;
        float il[4];
        #pragma unroll
        for (int r = 0; r < 4; r++)
            il[r] = __shfl(inv, (lane & 48) | (4 * g + r));
        #pragma unroll
        for (int ni = 0; ni < 4; ni++)
            #pragma unroll
            for (int r = 0; r < 4; r++) {
                int row = rbase + 4 * g + r;
                Y[(size_t)(b * 2048 + row) * 1024 + h * 64 + 16 * ni + c] =
                    f2b(o[ni][r] * il[r]);
            }
    }
}

// ---------------------------------------------------------------------------
extern "C" void kernel_launch(void* const* d_in, const int* in_sizes, int n_in,
                              void* d_out, int out_size, void* d_ws, size_t ws_size,
                              hipStream_t stream) {
    char* ws = (char*)d_ws;
    unsigned short* qb    = (unsigned short*)(ws);                  //  8 MB [b,t,C]
    unsigned short* kb    = (unsigned short*)(ws + 8388608);        //  8 MB [b,t,C]
    unsigned short* vt    = (unsigned short*)(ws + 16777216);       //  8 MB [bh,d,kv]
    unsigned short* Y     = (unsigned short*)(ws + 25165824);       //  8 MB [b,t,C]
    unsigned short* WqkvT = (unsigned short*)(ws + 33554432);       //  6 MB
    unsigned short* WoT   = (unsigned short*)(ws + 39845888);       //  2 MB
    unsigned short* xb    = (unsigned short*)(ws + 41943040);       //  8 MB
    unsigned short* bob   = (unsigned short*)(ws + 50331648);       //  2 KB
    int*            flag  = (int*)(ws + 50333696);

    prep_kernel<<<2049, 256, 0, stream>>>(
        d_in[0], d_in[1], d_in[2], d_in[3], xb, WqkvT, WoT, bob, flag,
        0.125f * 1.4426950408889634f);

    gemm_qkv<<<dim3(16, 32), 256, 0, stream>>>(xb, WqkvT, qb, kb, vt);

    attn_kernel<<<512, 256, 0, stream>>>(qb, kb, vt, Y);

    gemm_nt<<<dim3(16, 32), 256, 0, stream>>>(Y, WoT, d_out, bob, flag, 4096, 1024, 1024);
}

// Round 14
// 167.322 us; speedup vs baseline: 1.0192x; 1.0192x over previous
//
#include <hip/hip_runtime.h>
#include <hip/hip_bf16.h>
#include <math.h>

// B=2, T=2048, C=1024, H=16, D=64.  Inputs f32 (runtime-detected), compute bf16 MFMA.
// 4 launches: prep -> gemm_qkv (planar q/k + transposed V epilogue) -> attn -> gemm_nt.

typedef __attribute__((ext_vector_type(8))) short bf16x8;
typedef __attribute__((ext_vector_type(4))) float f32x4;

__device__ __forceinline__ float b2f(unsigned short u) {
    union { unsigned int i; float f; } x; x.i = ((unsigned int)u) << 16; return x.f;
}
__device__ __forceinline__ unsigned short f2b(float f) {
    __hip_bfloat16 h = __float2bfloat16(f);
    return *reinterpret_cast<unsigned short*>(&h);
}
__device__ __forceinline__ unsigned short f2b_rz(float f) {   // truncate (P only)
    union { float f; unsigned int i; } u; u.f = f; return (unsigned short)(u.i >> 16);
}
__device__ __forceinline__ float fexp2(float x) {
#if __has_builtin(__builtin_amdgcn_exp2f)
    return __builtin_amdgcn_exp2f(x);
#else
    return exp2f(x);
#endif
}
__device__ __forceinline__ void gload_lds16(const void* g, void* l) {
    __builtin_amdgcn_global_load_lds(
        (__attribute__((address_space(1))) void*)g,
        (__attribute__((address_space(3))) void*)l, 16, 0, 0);
}

// ---------------------------------------------------------------------------
// Fused prep: per-block dtype self-detect, then
//   blocks [0,1024): x -> xb (4096 elems each)
//   [1024,1792): Wqkv^T 64x64 tiles (Q cols scaled)   [1792,2048): Wo^T
//   2048: bias + publish flag
// Transpose fully vectorized: float4/ushort4 loads (16 B/lane), ushort4
// transposed stores (8 B/lane).
// ---------------------------------------------------------------------------
__device__ __forceinline__ void transpose_job64(
        const void* __restrict__ in, unsigned short* __restrict__ out,
        int Cc, int use_bf, int nscale, float scale,
        int c0, int r0, int tid, unsigned short (*t)[65]) {
    const unsigned short* inb = (const unsigned short*)in;
    const float* inf = (const float*)in;
    const int xl = (tid & 15) * 4;           // 4-col group within tile
    const int y  = tid >> 4;                 // 16 rows per pass
    const float sc = (c0 < nscale) ? scale : 1.0f;   // tile-uniform (c0 64-aligned)
    #pragma unroll
    for (int p = 0; p < 4; p++) {
        int row = y + 16 * p;
        float v0, v1, v2, v3;
        if (use_bf) {
            ushort4 u = *(const ushort4*)(inb + (size_t)(r0 + row) * Cc + c0 + xl);
            v0 = b2f(u.x); v1 = b2f(u.y); v2 = b2f(u.z); v3 = b2f(u.w);
        } else {
            float4 f = *(const float4*)(inf + (size_t)(r0 + row) * Cc + c0 + xl);
            v0 = f.x; v1 = f.y; v2 = f.z; v3 = f.w;
        }
        t[row][xl + 0] = f2b(v0 * sc);
        t[row][xl + 1] = f2b(v1 * sc);
        t[row][xl + 2] = f2b(v2 * sc);
        t[row][xl + 3] = f2b(v3 * sc);
    }
    __syncthreads();
    const int rr = (tid & 15) * 4;           // 4-row group of output
    const int cc = tid >> 4;
    #pragma unroll
    for (int p = 0; p < 4; p++) {
        int ccp = cc + 16 * p;
        ushort4 o4;
        o4.x = t[rr + 0][ccp];
        o4.y = t[rr + 1][ccp];
        o4.z = t[rr + 2][ccp];
        o4.w = t[rr + 3][ccp];
        *(ushort4*)(out + (size_t)(c0 + ccp) * 1024 + r0 + rr) = o4;
    }
}

__global__ __launch_bounds__(256) void prep_kernel(
        const void* __restrict__ xin, const void* __restrict__ Wqkv,
        const void* __restrict__ Wo, const void* __restrict__ bias,
        unsigned short* __restrict__ xb, unsigned short* __restrict__ WqkvT,
        unsigned short* __restrict__ WoT, unsigned short* __restrict__ bob,
        int* __restrict__ flag, float qscale) {
    __shared__ __align__(16) unsigned short t[64][65];
    __shared__ int det;
    const int tid = threadIdx.x, blk = blockIdx.x;

    if (tid < 64) {
        const unsigned short* xu = (const unsigned short*)xin;
        int cnt = 0;
        for (int i = tid; i < 1024; i += 64) {
            unsigned short u = xu[2 * i];
            int e = (u >> 7) & 0xFF;
            if (!((e == 0) || (e >= 96 && e <= 159))) cnt++;
        }
        #pragma unroll
        for (int m = 1; m < 64; m <<= 1) cnt += __shfl_xor(cnt, m);
        if (tid == 0) det = (cnt > 200) ? 0 : 1;
    }
    __syncthreads();
    const int use_bf = det;

    if (blk < 1024) {                       // x convert: 4096 elems/block
        int base = blk * 4096;
        #pragma unroll
        for (int i = 0; i < 4; i++) {
            int i4 = base + (tid + 256 * i) * 4;
            if (use_bf) {
                *(ushort4*)(xb + i4) = *(const ushort4*)((const unsigned short*)xin + i4);
            } else {
                float4 f = *(const float4*)((const float*)xin + i4);
                ushort4 o;
                o.x = f2b(f.x); o.y = f2b(f.y); o.z = f2b(f.z); o.w = f2b(f.w);
                *(ushort4*)(xb + i4) = o;
            }
        }
    } else if (blk < 1792) {                // Wqkv^T: 48 x 16 tiles of 64x64
        int tt = blk - 1024;
        int c0 = (tt % 48) * 64, r0 = (tt / 48) * 64;
        transpose_job64(Wqkv, WqkvT, 3072, use_bf, 1024, qscale, c0, r0, tid, t);
    } else if (blk < 2048) {                // Wo^T: 16 x 16 tiles
        int tt = blk - 1792;
        int c0 = (tt & 15) * 64, r0 = (tt >> 4) * 64;
        transpose_job64(Wo, WoT, 1024, use_bf, 0, 1.0f, c0, r0, tid, t);
    } else {
        int i4 = tid * 4;
        if (use_bf) {
            *(ushort4*)(bob + i4) = *(const ushort4*)((const unsigned short*)bias + i4);
        } else {
            float4 f = *(const float4*)((const float*)bias + i4);
            ushort4 o;
            o.x = f2b(f.x); o.y = f2b(f.y); o.z = f2b(f.z); o.w = f2b(f.w);
            *(ushort4*)(bob + i4) = o;
        }
        if (tid == 0) *flag = use_bf;
    }
}

// ---------------------------------------------------------------------------
// GEMM1: qkv = xb @ WqkvT^T.  128x192 (MxN) tiles -> grid (16,32) = 512 blocks
// = exactly 2 blocks/CU.  256 threads = 4 waves in 2x2; each wave owns 64x96
// (acc[4][6]).  LDS 40 KB.  (r6 measured winner)
// Swizzled LDS: elem (row,k) at row*64 + ((k>>3 ^ (row&7))<<3) + (k&7).
// ---------------------------------------------------------------------------
__global__ __launch_bounds__(256, 2) void gemm_qkv(
        const unsigned short* __restrict__ A, const unsigned short* __restrict__ Bt,
        unsigned short* __restrict__ qb, unsigned short* __restrict__ kb,
        unsigned short* __restrict__ vt) {
    __shared__ __align__(16) unsigned short lA[128 * 64];
    __shared__ __align__(16) unsigned short lB[192 * 64];
    const int tid  = threadIdx.x;
    const int wave = tid >> 6, lane = tid & 63;
    const int g = lane >> 4, c = lane & 15;
    const int m0 = blockIdx.y * 128, n0 = blockIdx.x * 192;
    const int wr = (wave >> 1) * 64;          // wave's M half (0 or 64)
    const int wc = (wave & 1) * 96;           // wave's N half (0 or 96)
    const int srow = lane >> 3;
    const int sc8  = ((lane & 7) ^ ((lane >> 3) & 7)) * 8;

    f32x4 acc[4][6] = {};

    for (int k0 = 0; k0 < 1024; k0 += 64) {
        #pragma unroll
        for (int i = 0; i < 4; i++) {         // A: 128 rows -> 16 segs (4/wave)
            int seg = wave * 4 + i;
            int row = seg * 8 + srow;
            gload_lds16(A  + (size_t)(m0 + row) * 1024 + k0 + sc8, lA + seg * 512);
        }
        #pragma unroll
        for (int i = 0; i < 6; i++) {         // B: 192 rows -> 24 segs (6/wave)
            int seg = wave * 6 + i;
            int row = seg * 8 + srow;
            gload_lds16(Bt + (size_t)(n0 + row) * 1024 + k0 + sc8, lB + seg * 512);
        }
        __syncthreads();

        #pragma unroll
        for (int dk = 0; dk < 2; dk++) {
            const int off = ((4 * dk + g) ^ (c & 7)) << 3;
            bf16x8 af[4], bfv[6];
            #pragma unroll
            for (int i = 0; i < 4; i++)
                af[i]  = *(const bf16x8*)(lA + (wr + 16 * i + c) * 64 + off);
            #pragma unroll
            for (int i = 0; i < 6; i++)
                bfv[i] = *(const bf16x8*)(lB + (wc + 16 * i + c) * 64 + off);
            #pragma unroll
            for (int mi = 0; mi < 4; mi++)
                #pragma unroll
                for (int ni = 0; ni < 6; ni++)
                    acc[mi][ni] = __builtin_amdgcn_mfma_f32_16x16x32_bf16(
                        af[mi], bfv[ni], acc[mi][ni], 0, 0, 0);
        }
        __syncthreads();
    }

    // Epilogue: per-fragment plane routing.  colbase is 16-aligned, so a
    // fragment (16 cols) never crosses a 64-aligned head or 1024-aligned
    // plane boundary.
    const int bb  = m0 >> 11;                 // batch (tile never crosses)
    const int kvb = (m0 & 2047) + wr;
    #pragma unroll
    for (int ni = 0; ni < 6; ni++) {
        const int colbase = n0 + wc + 16 * ni;
        if (colbase < 2048) {                 // q or k plane
            unsigned short* dst = (colbase < 1024) ? qb : kb;
            const int cb = (colbase & 1023) + c;
            #pragma unroll
            for (int mi = 0; mi < 4; mi++)
                #pragma unroll
                for (int r = 0; r < 4; r++) {
                    int row = m0 + wr + 16 * mi + 4 * g + r;
                    dst[(size_t)row * 1024 + cb] = f2b(acc[mi][ni][r]);
                }
        } else {                              // v -> vt[bh][d][kv]
            const int cc2 = colbase - 2048;
            const int hb  = cc2 >> 6;
            const int d   = (cc2 & 63) + c;
            const int bh  = bb * 16 + hb;
            #pragma unroll
            for (int mi = 0; mi < 4; mi++) {
                int kv = kvb + 16 * mi + 4 * g;   // rows r=0..3 consecutive
                ushort4 pk;
                pk.x = f2b(acc[mi][ni][0]); pk.y = f2b(acc[mi][ni][1]);
                pk.z = f2b(acc[mi][ni][2]); pk.w = f2b(acc[mi][ni][3]);
                *(ushort4*)(vt + ((size_t)bh * 64 + d) * 2048 + kv) = pk;
            }
        }
    }
}

// ---------------------------------------------------------------------------
// GEMM2: C = A @ Bt^T + bias.  128x64 tiles -> grid 512 (2 blocks/CU).
// ---------------------------------------------------------------------------
__global__ __launch_bounds__(256) void gemm_nt(
        const unsigned short* __restrict__ A, const unsigned short* __restrict__ Bt,
        void* __restrict__ C, const unsigned short* __restrict__ bias,
        const int* __restrict__ out_f32_flag, int M, int N, int K) {
    __shared__ __align__(16) unsigned short lA[128 * 64];
    __shared__ __align__(16) unsigned short lB[64 * 64];
    const int tid  = threadIdx.x;
    const int wave = tid >> 6, lane = tid & 63;
    const int g = lane >> 4, c = lane & 15;
    const int m0 = blockIdx.y * 128, n0 = blockIdx.x * 64;
    const int wm = wave * 32;
    const int srow = lane >> 3;
    const int sc8  = ((lane & 7) ^ ((lane >> 3) & 7)) * 8;

    f32x4 acc[2][4] = {};

    for (int k0 = 0; k0 < K; k0 += 64) {
        #pragma unroll
        for (int i = 0; i < 4; i++) {
            int seg = wave * 4 + i;
            int row = seg * 8 + srow;
            gload_lds16(A + (size_t)(m0 + row) * K + k0 + sc8, lA + seg * 512);
        }
        #pragma unroll
        for (int i = 0; i < 2; i++) {
            int seg = wave * 2 + i;
            int row = seg * 8 + srow;
            gload_lds16(Bt + (size_t)(n0 + row) * K + k0 + sc8, lB + seg * 512);
        }
        __syncthreads();

        #pragma unroll
        for (int dk = 0; dk < 2; dk++) {
            const int off = ((4 * dk + g) ^ (c & 7)) << 3;
            bf16x8 af[2], bfv[4];
            #pragma unroll
            for (int i = 0; i < 2; i++)
                af[i]  = *(const bf16x8*)(lA + (wm + 16 * i + c) * 64 + off);
            #pragma unroll
            for (int i = 0; i < 4; i++)
                bfv[i] = *(const bf16x8*)(lB + (16 * i + c) * 64 + off);
            #pragma unroll
            for (int mi = 0; mi < 2; mi++)
                #pragma unroll
                for (int ni = 0; ni < 4; ni++)
                    acc[mi][ni] = __builtin_amdgcn_mfma_f32_16x16x32_bf16(
                        af[mi], bfv[ni], acc[mi][ni], 0, 0, 0);
        }
        __syncthreads();
    }

    const bool f32out = out_f32_flag && (*out_f32_flag == 0);
    #pragma unroll
    for (int mi = 0; mi < 2; mi++)
        #pragma unroll
        for (int ni = 0; ni < 4; ni++)
            #pragma unroll
            for (int r = 0; r < 4; r++) {
                int row = m0 + wm + 16 * mi + 4 * g + r;
                int col = n0 + 16 * ni + c;
                float v = acc[mi][ni][r];
                if (bias) v += b2f(bias[col]);
                if (f32out) ((float*)C)[(size_t)row * N + col] = v;
                else ((unsigned short*)C)[(size_t)row * N + col] = f2b(v);
            }
}

// ---------------------------------------------------------------------------
// Flash attention, causal, fixed-offset softmax p = exp2(s - 12).
// S^T formulation, swizzled LDS, 64-row Q tiles.
// FUSED-PAIR SHARED STAGING (this round): the paired q-tiles j=jp and
// j=31-jp of the SAME bh share their K/V prefix (jp < 31-jp always), so the
// block stages each kv-tile ONCE (32-jp tiles vs 33 serial) and computes
// both items from the same staged buffer -- ~26% fewer staging phases and
// barriers.  Per-wave in-order LDS (r12-validated) makes the shared P buffer
// safe across the two back-to-back tile_compute calls.
// ---------------------------------------------------------------------------
template<bool MASKED>
__device__ __forceinline__ void tile_compute(
        const unsigned short* __restrict__ lKs, const unsigned short* __restrict__ lVts,
        unsigned short* __restrict__ P, const bf16x8* qB, f32x4* o,
        float& l_run, int wave, int lane, int g, int c) {
    const f32x4 sinit = {-12.f, -12.f, -12.f, -12.f};   // offset folded into acc init
    f32x4 s[4] = {sinit, sinit, sinit, sinit};
    #pragma unroll
    for (int nt = 0; nt < 4; nt++)
        #pragma unroll
        for (int dk = 0; dk < 2; dk++) {
            bf16x8 kA = *(const bf16x8*)(lKs + (16 * nt + c) * 64 + (((4 * dk + g) ^ (c & 7)) << 3));
            s[nt] = __builtin_amdgcn_mfma_f32_16x16x32_bf16(kA, qB[dk], s[nt], 0, 0, 0);
        }

    // V fragments: issue now -- LDS latency hides under the softmax VALU.
    bf16x8 vf[4][2];
    #pragma unroll
    for (int ni = 0; ni < 4; ni++)
        #pragma unroll
        for (int kk = 0; kk < 2; kk++)
            vf[ni][kk] = *(const bf16x8*)(lVts + (16 * ni + c) * 64 + (((4 * kk + g) ^ (c & 7)) << 3));

    float rsum = 0.f;
    #pragma unroll
    for (int nt = 0; nt < 4; nt++) {
        unsigned long long pk = 0;
        #pragma unroll
        for (int r = 0; r < 4; r++) {
            float v = s[nt][r];
            if (MASKED) v = (16 * nt + 4 * g + r <= 16 * wave + c) ? v : -1e30f;
            float p = fexp2(v);
            rsum += p;
            pk |= ((unsigned long long)f2b_rz(p)) << (16 * r);
        }
        int kvl = 16 * nt + 4 * g;    // 4-aligned; r=0..3 stay in the same 8-slot
        *(unsigned long long*)(P + c * 64 + (((kvl >> 3) ^ (c & 7)) << 3) + (kvl & 7)) = pk;
    }
    rsum += __shfl_xor(rsum, 16);
    rsum += __shfl_xor(rsum, 32);
    l_run += rsum;

    // Compiler-order fence only: per-wave LDS ops complete in order (HW), so
    // the pf reads (issued after the writes) see the new P without a waitcnt.
    __asm__ volatile("" ::: "memory");

    bf16x8 pf[2];
    #pragma unroll
    for (int kk = 0; kk < 2; kk++)
        pf[kk] = *(const bf16x8*)(P + c * 64 + (((4 * kk + g) ^ (c & 7)) << 3));
    #pragma unroll
    for (int ni = 0; ni < 4; ni++)
        #pragma unroll
        for (int kk = 0; kk < 2; kk++)
            o[ni] = __builtin_amdgcn_mfma_f32_16x16x32_bf16(pf[kk], vf[ni][kk], o[ni], 0, 0, 0);
    __asm__ volatile("" ::: "memory");   // pin pf reads before next call's P writes
}

__global__ __launch_bounds__(256, 2) void attn_kernel(
        const unsigned short* __restrict__ qb, const unsigned short* __restrict__ kb,
        const unsigned short* __restrict__ vt, unsigned short* __restrict__ Y) {
    __shared__ __align__(16) unsigned short lK[2][4096];
    __shared__ __align__(16) unsigned short lVt[2][4096];
    __shared__ __align__(16) unsigned short Pbuf[4][1024];

    const int tid = threadIdx.x, wave = tid >> 6, lane = tid & 63;
    const int g = lane >> 4, c = lane & 15;
    unsigned short* P = Pbuf[wave];
    const int srow = lane >> 3;
    const int sc8  = ((lane & 7) ^ ((lane >> 3) & 7)) * 8;

    // 512 uniform blocks: bh = blk & 31, jp = blk >> 5 (0..15).
    // Item A: q-tile j = jp (short); item B: q-tile j = 31 - jp (long).
    // Item A's kv range [0, jp] is a PREFIX of item B's [0, 31-jp] -> one
    // staging stream serves both.  Work per block = 33 chains, 32-jp stages.
    const int bh = blockIdx.x & 31;
    const int jp = blockIdx.x >> 5;
    const int b = bh >> 4, h = bh & 15;

    const unsigned short* Qb  = qb + (size_t)b * 2048 * 1024 + h * 64;
    const unsigned short* Kb  = kb + (size_t)b * 2048 * 1024 + h * 64;
    const unsigned short* Vtb = vt + (size_t)bh * 64 * 2048;

    const int q0a = jp * 64;              // item A diag tile base
    const int q0b = (31 - jp) * 64;       // item B diag tile base (> q0a)
    const int rba = q0a + 16 * wave;
    const int rbb = q0b + 16 * wave;

    bf16x8 qA[2], qBv[2];
    #pragma unroll
    for (int dk = 0; dk < 2; dk++) {
        qA[dk]  = *(const bf16x8*)(Qb + (size_t)(rba + c) * 1024 + 32 * dk + 8 * g);
        qBv[dk] = *(const bf16x8*)(Qb + (size_t)(rbb + c) * 1024 + 32 * dk + 8 * g);
    }

    f32x4 oa[4] = {}, ob[4] = {};
    float la = 0.f, lb = 0.f;

    #pragma unroll 1
    for (int kv0 = 0; kv0 <= q0b; kv0 += 128) {
        const bool do1 = (kv0 + 64 <= q0b);
        #pragma unroll
        for (int i = 0; i < 2; i++) {
            int seg = wave * 2 + i;
            int row = seg * 8 + srow;
            gload_lds16(Kb  + (size_t)(kv0 + row) * 1024 + sc8, lK[0] + seg * 512);
            gload_lds16(Vtb + (size_t)row * 2048 + kv0 + sc8,   lVt[0] + seg * 512);
            if (do1) {
                gload_lds16(Kb  + (size_t)(kv0 + 64 + row) * 1024 + sc8, lK[1] + seg * 512);
                gload_lds16(Vtb + (size_t)row * 2048 + kv0 + 64 + sc8,   lVt[1] + seg * 512);
            }
        }
        __syncthreads();

        // half 0: tile kv0
        if (kv0 == q0b)
            tile_compute<true >(lK[0], lVt[0], P, qBv, ob, lb, wave, lane, g, c);
        else
            tile_compute<false>(lK[0], lVt[0], P, qBv, ob, lb, wave, lane, g, c);
        if (kv0 <= q0a) {
            if (kv0 == q0a)
                tile_compute<true >(lK[0], lVt[0], P, qA, oa, la, wave, lane, g, c);
            else
                tile_compute<false>(lK[0], lVt[0], P, qA, oa, la, wave, lane, g, c);
        }
        // half 1: tile kv0 + 64
        if (do1) {
            const int kvt = kv0 + 64;
            if (kvt == q0b)
                tile_compute<true >(lK[1], lVt[1], P, qBv, ob, lb, wave, lane, g, c);
            else
                tile_compute<false>(lK[1], lVt[1], P, qBv, ob, lb, wave, lane, g, c);
            if (kvt <= q0a) {
                if (kvt == q0a)
                    tile_compute<true >(lK[1], lVt[1], P, qA, oa, la, wave, lane, g, c);
                else
                    tile_compute<false>(lK[1], lVt[1], P, qA, oa, la, wave, lane, g, c);
            }
        }
        __syncthreads();
    }

    float inva = 1.f / la, invb = 1.f / lb;
    float ila[4], ilb[4];
    #pragma unroll
    for (int r = 0; r < 4; r++) {
        ila[r] = __shfl(inva, (lane & 48) | (4 * g + r));
        ilb[r] = __shfl(invb, (lane & 48) | (4 * g + r));
    }
    #pragma unroll
    for (int ni = 0; ni < 4; ni++)
        #pragma unroll
        for (int r = 0; r < 4; r++) {
            Y[(size_t)(b * 2048 + rba + 4 * g + r) * 1024 + h * 64 + 16 * ni + c] =
                f2b(oa[ni][r] * ila[r]);
            Y[(size_t)(b * 2048 + rbb + 4 * g + r) * 1024 + h * 64 + 16 * ni + c] =
                f2b(ob[ni][r] * ilb[r]);
        }
}

// ---------------------------------------------------------------------------
extern "C" void kernel_launch(void* const* d_in, const int* in_sizes, int n_in,
                              void* d_out, int out_size, void* d_ws, size_t ws_size,
                              hipStream_t stream) {
    char* ws = (char*)d_ws;
    unsigned short* qb    = (unsigned short*)(ws);                  //  8 MB [b,t,C]
    unsigned short* kb    = (unsigned short*)(ws + 8388608);        //  8 MB [b,t,C]
    unsigned short* vt    = (unsigned short*)(ws + 16777216);       //  8 MB [bh,d,kv]
    unsigned short* Y     = (unsigned short*)(ws + 25165824);       //  8 MB [b,t,C]
    unsigned short* WqkvT = (unsigned short*)(ws + 33554432);       //  6 MB
    unsigned short* WoT   = (unsigned short*)(ws + 39845888);       //  2 MB
    unsigned short* xb    = (unsigned short*)(ws + 41943040);       //  8 MB
    unsigned short* bob   = (unsigned short*)(ws + 50331648);       //  2 KB
    int*            flag  = (int*)(ws + 50333696);

    prep_kernel<<<2049, 256, 0, stream>>>(
        d_in[0], d_in[1], d_in[2], d_in[3], xb, WqkvT, WoT, bob, flag,
        0.125f * 1.4426950408889634f);

    gemm_qkv<<<dim3(16, 32), 256, 0, stream>>>(xb, WqkvT, qb, kb, vt);

    attn_kernel<<<512, 256, 0, stream>>>(qb, kb, vt, Y);

    gemm_nt<<<dim3(16, 32), 256, 0, stream>>>(Y, WoT, d_out, bob, flag, 4096, 1024, 1024);
}